// Round 2
// baseline (497.704 us; speedup 1.0000x reference)
//
#include <hip/hip_runtime.h>

typedef unsigned short u16;
typedef __attribute__((ext_vector_type(8))) short bf16x8;
typedef __attribute__((ext_vector_type(4))) float f32x4;
typedef __attribute__((ext_vector_type(8))) unsigned short u16x8;

#define B_ 2
#define T_ 2048
#define C_ 2048
#define H_ 16
#define D_ 128
#define QKVW 6144  // 3*C

__device__ __forceinline__ u16 f2b(float f) {
  unsigned int x = __builtin_bit_cast(unsigned int, f);
  x += 0x7fffu + ((x >> 16) & 1u);   // round-to-nearest-even
  return (u16)(x >> 16);
}
__device__ __forceinline__ float b2f(u16 u) {
  unsigned int x = ((unsigned int)u) << 16;
  return __builtin_bit_cast(float, x);
}
__device__ __forceinline__ void gl_lds16(const void* g, void* l) {
  __builtin_amdgcn_global_load_lds((const __attribute__((address_space(1))) void*)g,
                                   (__attribute__((address_space(3))) void*)l, 16, 0, 0);
}

// ---------------- cast fp32 -> bf16 (8 elems/thread) ----------------
__global__ void castbf(const float* __restrict__ in, u16* __restrict__ out) {
  int i = blockIdx.x * 256 + threadIdx.x;
  f32x4 a = ((const f32x4*)in)[2 * i];
  f32x4 b = ((const f32x4*)in)[2 * i + 1];
  u16x8 o;
  o[0] = f2b(a[0]); o[1] = f2b(a[1]); o[2] = f2b(a[2]); o[3] = f2b(a[3]);
  o[4] = f2b(b[0]); o[5] = f2b(b[1]); o[6] = f2b(b[2]); o[7] = f2b(b[3]);
  ((u16x8*)out)[i] = o;
}

// ------------- cast + transpose: in [K][N] fp32 -> out [N][K] bf16 -------------
__global__ __launch_bounds__(256) void castT(const float* __restrict__ in,
                                             u16* __restrict__ out, int K, int N) {
  __shared__ __align__(16) u16 ld[64][72];
  const int nt = blockIdx.x * 64, kt = blockIdx.y * 64;
  const int tid = threadIdx.x;
#pragma unroll
  for (int s = 0; s < 4; ++s) {
    int idx = tid + s * 256;        // 0..1023
    int r = idx >> 4;               // k row 0..63
    int c = (idx & 15) * 4;         // n col
    f32x4 v = *(const f32x4*)(in + (size_t)(kt + r) * N + nt + c);
    ld[r][c] = f2b(v[0]); ld[r][c + 1] = f2b(v[1]);
    ld[r][c + 2] = f2b(v[2]); ld[r][c + 3] = f2b(v[3]);
  }
  __syncthreads();
#pragma unroll
  for (int s = 0; s < 2; ++s) {
    int idx = tid + s * 256;        // 0..511
    int n = idx >> 3;               // 0..63
    int c8 = (idx & 7) * 8;         // k offset
    u16x8 o;
#pragma unroll
    for (int j = 0; j < 8; ++j) o[j] = ld[c8 + j][n];
    *(u16x8*)(out + (size_t)(nt + n) * K + kt + c8) = o;
  }
}

// ---------------- 256x256 8-phase GEMM (m201-style), bf16 MFMA ----------------
// R2 fix: FULL 3-bit G4 swizzle (chunk ^= row&7) — R1 used 1 bit, which only
// pair-swapped two bank groups (conflicts 12.6M->9.4M, no win). With 3 bits
// every 8-lane b128 group covers all 8 16B-chunk positions = all 32 banks.
// Linear LDS dest (global_load_lds) + inverse-swizzled SOURCE + swizzled read.
__device__ __forceinline__ void stage_chunk(const u16* __restrict__ g, int K,
                                            u16* l, int ch) {
  int row = ch >> 3;
  int c = (ch & 7) ^ (row & 7);                 // inverse swizzle on source
  gl_lds16(g + (size_t)row * K + c * 8, l + ch * 8);
}

#define MFMA_Q(AF, BF, MH, NH)                                               \
  _Pragma("unroll")                                                          \
  for (int mi = 0; mi < 4; ++mi) {                                           \
    _Pragma("unroll")                                                        \
    for (int ni = 0; ni < 2; ++ni) {                                         \
      _Pragma("unroll")                                                      \
      for (int ks = 0; ks < 2; ++ks)                                         \
        acc[(MH)*4 + mi][(NH)*2 + ni] =                                      \
            __builtin_amdgcn_mfma_f32_16x16x32_bf16(                         \
                AF[mi][ks], BF[ni][ks], acc[(MH)*4 + mi][(NH)*2 + ni],       \
                0, 0, 0);                                                    \
    }                                                                        \
  }

template <int OUT_BF16>
__global__ __launch_bounds__(512, 2) void gemm256(const u16* __restrict__ A,
                                                  const u16* __restrict__ Bt,
                                                  void* __restrict__ Cout,
                                                  int M, int N, int K) {
  __shared__ __align__(16) u16 sm[65536];   // 128 KiB: 2 bufs x (A 32KB | B 32KB)
  const int tid = threadIdx.x;
  const int lane = tid & 63, w = tid >> 6;
  const int quad = lane >> 4, l15 = lane & 15;
  const int wm = w >> 2, wn = w & 3;        // 2 x 4 wave grid, per-wave C 128x64
  const int NXT = N >> 8;
  int id = blockIdx.x;
  const int cpx = gridDim.x >> 3;           // grid % 8 == 0 (384 / 128)
  id = (id & 7) * cpx + (id >> 3);          // XCD-contiguous chunks
  const int tn0 = (id % NXT) * 256, tm0 = (id / NXT) * 256;
  const int NT = K >> 6;
  const u16* Ag = A + (size_t)tm0 * K;
  const u16* Bg = Bt + (size_t)tn0 * K;

  f32x4 acc[8][4] = {};
  bf16x8 a0[4][2], a1[4][2], b0[2][2], b1[2][2];

  auto stA = [&](int tt, int half) {        // half 0 -> U1, 1 -> U3
    u16* l = &sm[(tt & 1) * 32768];
    const u16* g = Ag + tt * 64;
    stage_chunk(g, K, l, half * 512 + tid);
    stage_chunk(g, K, l, 1024 + half * 512 + tid);
  };
  auto stB = [&](int tt, int nh) {          // nh 0 -> U2, 1 -> U4
    u16* l = &sm[(tt & 1) * 32768 + 16384];
    const u16* g = Bg + tt * 64;
    int ch = nh * 256 + (tid & 255) + ((tid >> 8) << 9);
    stage_chunk(g, K, l, ch);
    stage_chunk(g, K, l, ch + 1024);
  };

  // prologue: T0.U1-U4, T1.U1-U3 (7 units in flight), retire T0, keep 3
  stA(0, 0); stB(0, 0); stA(0, 1); stB(0, 1);
  if (NT > 1) {
    stA(1, 0); stB(1, 0); stA(1, 1);
    asm volatile("s_waitcnt vmcnt(6)" ::: "memory");
  } else {
    asm volatile("s_waitcnt vmcnt(0)" ::: "memory");
  }
  __builtin_amdgcn_s_barrier();

  for (int t = 0; t < NT; ++t) {
    const u16* LA = &sm[(t & 1) * 32768];
    const u16* LB = LA + 16384;
    // ---- P1: read a0 (8) + b0 (4); stage (t+1).U4; MFMA Q1 ----
#pragma unroll
    for (int mi = 0; mi < 4; ++mi)
#pragma unroll
      for (int ks = 0; ks < 2; ++ks) {
        int r = wm * 128 + mi * 16 + l15;
        a0[mi][ks] = *(const bf16x8*)&LA[r * 64 +
                     ((ks * 32 + quad * 8) ^ ((r & 7) << 3))];
      }
#pragma unroll
    for (int ni = 0; ni < 2; ++ni)
#pragma unroll
      for (int ks = 0; ks < 2; ++ks) {
        int r = wn * 64 + ni * 16 + l15;
        b0[ni][ks] = *(const bf16x8*)&LB[r * 64 +
                     ((ks * 32 + quad * 8) ^ ((r & 7) << 3))];
      }
    if (t + 1 < NT) stB(t + 1, 1);
    __builtin_amdgcn_s_barrier();
    asm volatile("s_waitcnt lgkmcnt(0)");
    __builtin_amdgcn_sched_barrier(0);
    __builtin_amdgcn_s_setprio(1);
    MFMA_Q(a0, b0, 0, 0);
    __builtin_amdgcn_s_setprio(0);
    __builtin_amdgcn_s_barrier();
    // ---- P2: read b1 (4); stage (t+2).U1; MFMA Q2 ----
#pragma unroll
    for (int ni = 0; ni < 2; ++ni)
#pragma unroll
      for (int ks = 0; ks < 2; ++ks) {
        int r = wn * 64 + (ni + 2) * 16 + l15;
        b1[ni][ks] = *(const bf16x8*)&LB[r * 64 +
                     ((ks * 32 + quad * 8) ^ ((r & 7) << 3))];
      }
    if (t + 2 < NT) stA(t + 2, 0);
    __builtin_amdgcn_s_barrier();
    asm volatile("s_waitcnt lgkmcnt(0)");
    __builtin_amdgcn_sched_barrier(0);
    __builtin_amdgcn_s_setprio(1);
    MFMA_Q(a0, b1, 0, 1);
    __builtin_amdgcn_s_setprio(0);
    __builtin_amdgcn_s_barrier();
    // ---- P3: read a1 (8); stage (t+2).U2; MFMA Q3 ----
#pragma unroll
    for (int mi = 0; mi < 4; ++mi)
#pragma unroll
      for (int ks = 0; ks < 2; ++ks) {
        int r = wm * 128 + (mi + 4) * 16 + l15;
        a1[mi][ks] = *(const bf16x8*)&LA[r * 64 +
                     ((ks * 32 + quad * 8) ^ ((r & 7) << 3))];
      }
    if (t + 2 < NT) stB(t + 2, 0);
    __builtin_amdgcn_s_barrier();
    asm volatile("s_waitcnt lgkmcnt(0)");
    __builtin_amdgcn_sched_barrier(0);
    __builtin_amdgcn_s_setprio(1);
    MFMA_Q(a1, b1, 1, 1);
    __builtin_amdgcn_s_setprio(0);
    __builtin_amdgcn_s_barrier();
    // ---- P4: stage (t+2).U3; counted vmcnt; MFMA Q4 ----
    if (t + 2 < NT) {
      stA(t + 2, 1);
      asm volatile("s_waitcnt vmcnt(6)" ::: "memory");
    } else {
      asm volatile("s_waitcnt vmcnt(0)" ::: "memory");
    }
    __builtin_amdgcn_s_barrier();
    __builtin_amdgcn_s_setprio(1);
    MFMA_Q(a1, b0, 1, 0);
    __builtin_amdgcn_s_setprio(0);
    __builtin_amdgcn_s_barrier();
  }

  // epilogue: C/D layout col=lane&15, row=quad*4+reg
#pragma unroll
  for (int mi = 0; mi < 8; ++mi)
#pragma unroll
    for (int ni = 0; ni < 4; ++ni)
#pragma unroll
      for (int r = 0; r < 4; ++r) {
        int row = tm0 + wm * 128 + mi * 16 + quad * 4 + r;
        int col = tn0 + wn * 64 + ni * 16 + l15;
        float v = acc[mi][ni][r];
        if (OUT_BF16) ((u16*)Cout)[(size_t)row * N + col] = f2b(v);
        else          ((float*)Cout)[(size_t)row * N + col] = v;
      }
}

// ---------------- RoPE in-place on q,k of qkv (bf16) ----------------
__global__ void rope_k(u16* __restrict__ qkv) {
  int idx = blockIdx.x * 256 + threadIdx.x;   // 0 .. 2^23-1
  int i = idx & 63;
  int h = (idx >> 6) & 15;
  int which = (idx >> 10) & 1;
  int t = (idx >> 11) & 2047;
  int b = idx >> 22;
  size_t base = (size_t)(b * T_ + t) * QKVW + which * 2048 + h * 128 + i;
  float t1 = b2f(qkv[base]), t2 = b2f(qkv[base + 64]);
  // div_i = 10000^(-i/64) ; log2(10000)/64 = 0.20762050593046439
  float ang = (float)t * exp2f(-(float)i * 0.20762050593046439f);
  float sn, cs;
  sincosf(ang, &sn, &cs);
  qkv[base]      = f2b(t1 * cs - t2 * sn);
  qkv[base + 64] = f2b(t2 * cs + t1 * sn);
}

// ---------------- transpose V -> Vt [B*H][D][T] (bf16) ----------------
__global__ __launch_bounds__(256) void vtrans(const u16* __restrict__ qkv, u16* __restrict__ vt) {
  __shared__ __align__(16) u16 ld[128][136];
  const int tt = blockIdx.x, bh = blockIdx.y;
  const int b = bh >> 4, h = bh & 15;
  const u16* vb = qkv + (size_t)b * T_ * QKVW + 4096 + h * 128;
  const int tid = threadIdx.x;
#pragma unroll
  for (int s = 0; s < 8; ++s) {
    int t = (tid >> 4) + s * 16;
    int d0 = (tid & 15) * 8;
    *(bf16x8*)&ld[t][d0] = *(const bf16x8*)(vb + (size_t)(tt * 128 + t) * QKVW + d0);
  }
  __syncthreads();
  u16* vout = vt + (size_t)bh * D_ * T_ + tt * 128;
#pragma unroll
  for (int s = 0; s < 8; ++s) {
    int d = (tid >> 4) + s * 16;
    int t0 = (tid & 15) * 8;
    u16x8 o;
#pragma unroll
    for (int j = 0; j < 8; ++j) o[j] = ld[t0 + j][d];
    *(u16x8*)(vout + (size_t)d * T_ + t0) = o;
  }
}

// ---------------- flash attention (causal, online softmax) ----------------
// R2: causal-PAIRED blocks. R1 post-mortem: grid (bh,j)=1024 blocks = exactly
// 4/CU all resident at t=0, work ∝ j+1 (1..33) -> makespan = the j=31 blocks,
// OccupancyPercent 4.7%, MfmaUtil 2.4%. Fix: block (bh, jp) owns q-tiles
// jA=jp and jB=31-jp: every block computes exactly 33 tile-iterations on a
// K/V tile staged ONCE for both. Also: global_load_lds staging with 3-bit
// XOR swizzle (no VGPR round-trip, no padding), K/V double-buffered (stage
// kt+1 overlaps compute kt), P in dedicated buffer (wave-private -> single
// barrier per iteration), T13 defer-max (skip O-rescale when rowmax growth
// <= 11.5 in log2 units; P bounded by 2^11.5, f32 accum safe).
// NOTE reference gotcha: out = einsum('bhts,bshd->bhtd').reshape(B,T,C) is a
// FLAT reshape of (B,H,T,D): element (b,h,t,d) sits at ((b*H+h)*T+t)*D+d.
#define APW 72    // P tile row stride (u16)
__global__ __launch_bounds__(256, 3) void attn(const u16* __restrict__ qkv,
                                               const u16* __restrict__ vt,
                                               u16* __restrict__ obuf) {
  __shared__ __align__(16) u16 lK[2][64 * 128];    // 2 x 16 KB, swizzled
  __shared__ __align__(16) u16 lV[2][128 * 64];    // 2 x 16 KB, swizzled
  __shared__ __align__(16) u16 lP[64 * APW];       // 9 KB, wave-private rows
  const int tid = threadIdx.x, lane = tid & 63, w = tid >> 6;
  const int quad = lane >> 4, l15 = lane & 15;
  const int bh = blockIdx.x, jp = blockIdx.y;
  const int jA = jp, jB = 31 - jp;                 // jA in 0..15, jB in 16..31
  const int b = bh >> 4, h = bh & 15;
  const u16* qb = qkv + (size_t)b * T_ * QKVW + h * 128;
  const u16* kb = qb + 2048;
  const u16* vtb = vt + (size_t)bh * D_ * T_;

  bf16x8 qfA[4], qfB[4];
#pragma unroll
  for (int kk = 0; kk < 4; ++kk) {
    qfA[kk] = *(const bf16x8*)(qb + (size_t)(jA * 64 + w * 16 + l15) * QKVW + kk * 32 + quad * 8);
    qfB[kk] = *(const bf16x8*)(qb + (size_t)(jB * 64 + w * 16 + l15) * QKVW + kk * 32 + quad * 8);
  }

  f32x4 oA[8] = {}, oB[8] = {};
  float mA[4], lAr[4], mB[4], lBr[4];
#pragma unroll
  for (int r = 0; r < 4; ++r) {
    mA[r] = -__builtin_inff(); lAr[r] = 0.f;
    mB[r] = -__builtin_inff(); lBr[r] = 0.f;
  }
  const float sc = 0.08838834764831845f * 1.4426950408889634f;  // 1/sqrt(128) * log2(e)

  // stage K tile [64 key][128 d] and Vt tile [128 d][64 key] via global_load_lds,
  // linear LDS dest + inverse-swizzled global source (G4 3-bit XOR).
  auto stage = [&](int kt, int buf) {
#pragma unroll
    for (int s = 0; s < 4; ++s) {
      int ch = tid + s * 256;                        // 0..1023
      int kr = ch >> 4, kc = (ch & 15) ^ (kr & 7);   // K row 0..63, 16 chunks/row
      gl_lds16(kb + (size_t)(kt * 64 + kr) * QKVW + kc * 8, &lK[buf][ch * 8]);
      int vr = ch >> 3, vc = (ch & 7) ^ (vr & 7);    // V row 0..127, 8 chunks/row
      gl_lds16(vtb + (size_t)vr * T_ + kt * 64 + vc * 8, &lV[buf][ch * 8]);
    }
  };

  auto tile_compute = [&](const bf16x8* qf, f32x4* oacc, float* mrow, float* lrow,
                          int jw, int kt, int cb) {
    // S = Q K^T   (16 q-rows x 64 keys per wave)
    f32x4 sacc[4] = {};
#pragma unroll
    for (int kk = 0; kk < 4; ++kk) {
      bf16x8 kf[4];
#pragma unroll
      for (int nj = 0; nj < 4; ++nj) {
        int r = nj * 16 + l15;
        kf[nj] = *(const bf16x8*)&lK[cb][r * 128 + ((kk * 32 + quad * 8) ^ ((r & 7) << 3))];
      }
#pragma unroll
      for (int nj = 0; nj < 4; ++nj)
        sacc[nj] = __builtin_amdgcn_mfma_f32_16x16x32_bf16(qf[kk], kf[nj], sacc[nj], 0, 0, 0);
    }
    const bool diag = (kt == jw);
#pragma unroll
    for (int nj = 0; nj < 4; ++nj) {
      int key = nj * 16 + l15;                 // local key 0..63
#pragma unroll
      for (int r = 0; r < 4; ++r) {
        float s = sacc[nj][r] * sc;
        if (diag) {
          int qrow = w * 16 + quad * 4 + r;    // local q 0..63
          if (key > qrow) s = -__builtin_inff();
        }
        sacc[nj][r] = s;
      }
    }
#pragma unroll
    for (int r = 0; r < 4; ++r) {
      float rm = sacc[0][r];
#pragma unroll
      for (int nj = 1; nj < 4; ++nj) rm = fmaxf(rm, sacc[nj][r]);
      rm = fmaxf(rm, __shfl_xor(rm, 1));
      rm = fmaxf(rm, __shfl_xor(rm, 2));
      rm = fmaxf(rm, __shfl_xor(rm, 4));
      rm = fmaxf(rm, __shfl_xor(rm, 8));
      float mold = mrow[r];
      float mnew = mold;
      if (rm > mold + 11.5f) {                 // T13 defer-max: rescale only on real growth
        mnew = rm;
        float alpha = exp2f(mold - mnew);
#pragma unroll
        for (int nd = 0; nd < 8; ++nd) oacc[nd][r] *= alpha;
        lrow[r] *= alpha;
        mrow[r] = mnew;
      }
      float rs = 0.f;
      int prow = w * 16 + quad * 4 + r;        // wave-private P row
#pragma unroll
      for (int nj = 0; nj < 4; ++nj) {
        float p = exp2f(sacc[nj][r] - mnew);
        rs += p;
        lP[prow * APW + nj * 16 + l15] = f2b(p);
      }
      rs += __shfl_xor(rs, 1);
      rs += __shfl_xor(rs, 2);
      rs += __shfl_xor(rs, 4);
      rs += __shfl_xor(rs, 8);
      lrow[r] += rs;
    }
    // PV: O += P * V  (P rows wave-private — no barrier needed)
#pragma unroll
    for (int kk = 0; kk < 2; ++kk) {
      bf16x8 pf, vf[8];
      pf = *(const bf16x8*)&lP[(w * 16 + l15) * APW + kk * 32 + quad * 8];
#pragma unroll
      for (int nd = 0; nd < 8; ++nd) {
        int r = nd * 16 + l15;
        vf[nd] = *(const bf16x8*)&lV[cb][r * 64 + ((kk * 32 + quad * 8) ^ ((r & 7) << 3))];
      }
#pragma unroll
      for (int nd = 0; nd < 8; ++nd)
        oacc[nd] = __builtin_amdgcn_mfma_f32_16x16x32_bf16(pf, vf[nd], oacc[nd], 0, 0, 0);
    }
  };

  stage(0, 0);
  __syncthreads();   // drains vmcnt (implicit in __syncthreads)

  for (int kt = 0; kt <= jB; ++kt) {
    int cb = kt & 1;
    if (kt < jB) stage(kt + 1, cb ^ 1);       // overlap next-tile DMA with compute
    tile_compute(qfB, oB, mB, lBr, jB, kt, cb);
    if (kt <= jA) tile_compute(qfA, oA, mA, lAr, jA, kt, cb);
    __syncthreads();                          // drains stage DMA + LDS, swap bufs
  }

  // epilogue: O / l -> bf16, REFERENCE-MATCHED layout [B*H][T][D] (see note)
#pragma unroll
  for (int nd = 0; nd < 8; ++nd)
#pragma unroll
    for (int r = 0; r < 4; ++r) {
      int dcol = nd * 16 + l15;
      int qrB = jB * 64 + w * 16 + quad * 4 + r;
      obuf[((size_t)bh * T_ + qrB) * D_ + dcol] = f2b(oB[nd][r] / lBr[r]);
      int qrA = jA * 64 + w * 16 + quad * 4 + r;
      obuf[((size_t)bh * T_ + qrA) * D_ + dcol] = f2b(oA[nd][r] / lAr[r]);
    }
}

extern "C" void kernel_launch(void* const* d_in, const int* in_sizes, int n_in,
                              void* d_out, int out_size, void* d_ws, size_t ws_size,
                              hipStream_t stream) {
  const float* x = (const float*)d_in[0];
  const float* Wqkv = (const float*)d_in[1];
  const float* Wout = (const float*)d_in[2];
  float* out = (float*)d_out;
  char* ws = (char*)d_ws;

  // workspace layout (bytes):
  //   [0,            16777216)  xb (x bf16)   -- later reused as Ob (attn out bf16)
  //   [16777216,     41943040)  Wqkv_t bf16   -- later reused as Wout_t bf16
  //   [41943040,     92274688)  qkv bf16 [4096][6144]
  //   [92274688,    109051904)  Vt bf16 [B*H][128][2048]
  u16* xb   = (u16*)ws;
  u16* wqt  = (u16*)(ws + 16777216);
  u16* qkvb = (u16*)(ws + 41943040);
  u16* vtb  = (u16*)(ws + 92274688);
  u16* wot  = wqt;   // alias: cast after GEMM1 consumed Wqkv_t
  u16* ob   = xb;    // alias: attn output after GEMM1 consumed xb

  castbf<<<4096, 256, 0, stream>>>(x, xb);                                  // 8.4M elems
  castT<<<dim3(96, 32), 256, 0, stream>>>(Wqkv, wqt, 2048, 6144);
  gemm256<1><<<dim3(384), 512, 0, stream>>>(xb, wqt, qkvb, 4096, 6144, 2048);
  castT<<<dim3(32, 32), 256, 0, stream>>>(Wout, wot, 2048, 2048);
  rope_k<<<32768, 256, 0, stream>>>(qkvb);
  vtrans<<<dim3(16, 32), 256, 0, stream>>>(qkvb, vtb);
  attn<<<dim3(32, 16), 256, 0, stream>>>(qkvb, vtb, ob);   // (bh, jpair)
  gemm256<0><<<dim3(128), 512, 0, stream>>>(ob, wot, out, 4096, 2048, 2048);
}

// Round 3
// 410.596 us; speedup vs baseline: 1.2122x; 1.2122x over previous
//
#include <hip/hip_runtime.h>

typedef unsigned short u16;
typedef __attribute__((ext_vector_type(8))) short bf16x8;
typedef __attribute__((ext_vector_type(4))) float f32x4;
typedef __attribute__((ext_vector_type(8))) unsigned short u16x8;

#define B_ 2
#define T_ 2048
#define C_ 2048
#define H_ 16
#define D_ 128
#define QKVW 6144  // 3*C

__device__ __forceinline__ u16 f2b(float f) {
  unsigned int x = __builtin_bit_cast(unsigned int, f);
  x += 0x7fffu + ((x >> 16) & 1u);   // round-to-nearest-even
  return (u16)(x >> 16);
}
__device__ __forceinline__ float b2f(u16 u) {
  unsigned int x = ((unsigned int)u) << 16;
  return __builtin_bit_cast(float, x);
}
__device__ __forceinline__ void gl_lds16(const void* g, void* l) {
  __builtin_amdgcn_global_load_lds((const __attribute__((address_space(1))) void*)g,
                                   (__attribute__((address_space(3))) void*)l, 16, 0, 0);
}

// ---------------- cast fp32 -> bf16 (8 elems/thread) ----------------
__global__ void castbf(const float* __restrict__ in, u16* __restrict__ out) {
  int i = blockIdx.x * 256 + threadIdx.x;
  f32x4 a = ((const f32x4*)in)[2 * i];
  f32x4 b = ((const f32x4*)in)[2 * i + 1];
  u16x8 o;
  o[0] = f2b(a[0]); o[1] = f2b(a[1]); o[2] = f2b(a[2]); o[3] = f2b(a[3]);
  o[4] = f2b(b[0]); o[5] = f2b(b[1]); o[6] = f2b(b[2]); o[7] = f2b(b[3]);
  ((u16x8*)out)[i] = o;
}

// ------------- cast + transpose: in [K][N] fp32 -> out [N][K] bf16 -------------
__global__ __launch_bounds__(256) void castT(const float* __restrict__ in,
                                             u16* __restrict__ out, int K, int N) {
  __shared__ __align__(16) u16 ld[64][72];
  const int nt = blockIdx.x * 64, kt = blockIdx.y * 64;
  const int tid = threadIdx.x;
#pragma unroll
  for (int s = 0; s < 4; ++s) {
    int idx = tid + s * 256;        // 0..1023
    int r = idx >> 4;               // k row 0..63
    int c = (idx & 15) * 4;         // n col
    f32x4 v = *(const f32x4*)(in + (size_t)(kt + r) * N + nt + c);
    ld[r][c] = f2b(v[0]); ld[r][c + 1] = f2b(v[1]);
    ld[r][c + 2] = f2b(v[2]); ld[r][c + 3] = f2b(v[3]);
  }
  __syncthreads();
#pragma unroll
  for (int s = 0; s < 2; ++s) {
    int idx = tid + s * 256;        // 0..511
    int n = idx >> 3;               // 0..63
    int c8 = (idx & 7) * 8;         // k offset
    u16x8 o;
#pragma unroll
    for (int j = 0; j < 8; ++j) o[j] = ld[c8 + j][n];
    *(u16x8*)(out + (size_t)(nt + n) * K + kt + c8) = o;
  }
}

// ---------------- 256x256 8-phase GEMM (m201-style), bf16 MFMA ----------------
// Full 3-bit G4 swizzle (chunk ^= row&7): every 8-lane b128 group covers all
// 8 16B-chunk positions = all 32 banks. Linear LDS dest (global_load_lds) +
// pre-swizzled SOURCE + swizzled read (rule #21).
__device__ __forceinline__ void stage_chunk(const u16* __restrict__ g, int K,
                                            u16* l, int ch) {
  int row = ch >> 3;
  int c = (ch & 7) ^ (row & 7);                 // inverse swizzle on source
  gl_lds16(g + (size_t)row * K + c * 8, l + ch * 8);
}

#define MFMA_Q(AF, BF, MH, NH)                                               \
  _Pragma("unroll")                                                          \
  for (int mi = 0; mi < 4; ++mi) {                                           \
    _Pragma("unroll")                                                        \
    for (int ni = 0; ni < 2; ++ni) {                                         \
      _Pragma("unroll")                                                      \
      for (int ks = 0; ks < 2; ++ks)                                         \
        acc[(MH)*4 + mi][(NH)*2 + ni] =                                      \
            __builtin_amdgcn_mfma_f32_16x16x32_bf16(                         \
                AF[mi][ks], BF[ni][ks], acc[(MH)*4 + mi][(NH)*2 + ni],       \
                0, 0, 0);                                                    \
    }                                                                        \
  }

template <int OUT_BF16>
__global__ __launch_bounds__(512, 2) void gemm256(const u16* __restrict__ A,
                                                  const u16* __restrict__ Bt,
                                                  void* __restrict__ Cout,
                                                  int M, int N, int K) {
  __shared__ __align__(16) u16 sm[65536];   // 128 KiB: 2 bufs x (A 32KB | B 32KB)
  const int tid = threadIdx.x;
  const int lane = tid & 63, w = tid >> 6;
  const int quad = lane >> 4, l15 = lane & 15;
  const int wm = w >> 2, wn = w & 3;        // 2 x 4 wave grid, per-wave C 128x64
  const int NXT = N >> 8;
  int id = blockIdx.x;
  const int cpx = gridDim.x >> 3;           // grid % 8 == 0 (384 / 128)
  id = (id & 7) * cpx + (id >> 3);          // XCD-contiguous chunks
  const int tn0 = (id % NXT) * 256, tm0 = (id / NXT) * 256;
  const int NT = K >> 6;
  const u16* Ag = A + (size_t)tm0 * K;
  const u16* Bg = Bt + (size_t)tn0 * K;

  f32x4 acc[8][4] = {};
  bf16x8 a0[4][2], a1[4][2], b0[2][2], b1[2][2];

  auto stA = [&](int tt, int half) {        // half 0 -> U1, 1 -> U3
    u16* l = &sm[(tt & 1) * 32768];
    const u16* g = Ag + tt * 64;
    stage_chunk(g, K, l, half * 512 + tid);
    stage_chunk(g, K, l, 1024 + half * 512 + tid);
  };
  auto stB = [&](int tt, int nh) {          // nh 0 -> U2, 1 -> U4
    u16* l = &sm[(tt & 1) * 32768 + 16384];
    const u16* g = Bg + tt * 64;
    int ch = nh * 256 + (tid & 255) + ((tid >> 8) << 9);
    stage_chunk(g, K, l, ch);
    stage_chunk(g, K, l, ch + 1024);
  };

  // prologue: T0.U1-U4, T1.U1-U3 (7 units in flight), retire T0, keep 3
  stA(0, 0); stB(0, 0); stA(0, 1); stB(0, 1);
  if (NT > 1) {
    stA(1, 0); stB(1, 0); stA(1, 1);
    asm volatile("s_waitcnt vmcnt(6)" ::: "memory");
  } else {
    asm volatile("s_waitcnt vmcnt(0)" ::: "memory");
  }
  __builtin_amdgcn_s_barrier();

  for (int t = 0; t < NT; ++t) {
    const u16* LA = &sm[(t & 1) * 32768];
    const u16* LB = LA + 16384;
    // ---- P1: read a0 (8) + b0 (4); stage (t+1).U4; MFMA Q1 ----
#pragma unroll
    for (int mi = 0; mi < 4; ++mi)
#pragma unroll
      for (int ks = 0; ks < 2; ++ks) {
        int r = wm * 128 + mi * 16 + l15;
        a0[mi][ks] = *(const bf16x8*)&LA[r * 64 +
                     ((ks * 32 + quad * 8) ^ ((r & 7) << 3))];
      }
#pragma unroll
    for (int ni = 0; ni < 2; ++ni)
#pragma unroll
      for (int ks = 0; ks < 2; ++ks) {
        int r = wn * 64 + ni * 16 + l15;
        b0[ni][ks] = *(const bf16x8*)&LB[r * 64 +
                     ((ks * 32 + quad * 8) ^ ((r & 7) << 3))];
      }
    if (t + 1 < NT) stB(t + 1, 1);
    __builtin_amdgcn_s_barrier();
    asm volatile("s_waitcnt lgkmcnt(0)");
    __builtin_amdgcn_sched_barrier(0);
    __builtin_amdgcn_s_setprio(1);
    MFMA_Q(a0, b0, 0, 0);
    __builtin_amdgcn_s_setprio(0);
    __builtin_amdgcn_s_barrier();
    // ---- P2: read b1 (4); stage (t+2).U1; MFMA Q2 ----
#pragma unroll
    for (int ni = 0; ni < 2; ++ni)
#pragma unroll
      for (int ks = 0; ks < 2; ++ks) {
        int r = wn * 64 + (ni + 2) * 16 + l15;
        b1[ni][ks] = *(const bf16x8*)&LB[r * 64 +
                     ((ks * 32 + quad * 8) ^ ((r & 7) << 3))];
      }
    if (t + 2 < NT) stA(t + 2, 0);
    __builtin_amdgcn_s_barrier();
    asm volatile("s_waitcnt lgkmcnt(0)");
    __builtin_amdgcn_sched_barrier(0);
    __builtin_amdgcn_s_setprio(1);
    MFMA_Q(a0, b1, 0, 1);
    __builtin_amdgcn_s_setprio(0);
    __builtin_amdgcn_s_barrier();
    // ---- P3: read a1 (8); stage (t+2).U2; MFMA Q3 ----
#pragma unroll
    for (int mi = 0; mi < 4; ++mi)
#pragma unroll
      for (int ks = 0; ks < 2; ++ks) {
        int r = wm * 128 + (mi + 4) * 16 + l15;
        a1[mi][ks] = *(const bf16x8*)&LA[r * 64 +
                     ((ks * 32 + quad * 8) ^ ((r & 7) << 3))];
      }
    if (t + 2 < NT) stB(t + 2, 0);
    __builtin_amdgcn_s_barrier();
    asm volatile("s_waitcnt lgkmcnt(0)");
    __builtin_amdgcn_sched_barrier(0);
    __builtin_amdgcn_s_setprio(1);
    MFMA_Q(a1, b1, 1, 1);
    __builtin_amdgcn_s_setprio(0);
    __builtin_amdgcn_s_barrier();
    // ---- P4: stage (t+2).U3; counted vmcnt; MFMA Q4 ----
    if (t + 2 < NT) {
      stA(t + 2, 1);
      asm volatile("s_waitcnt vmcnt(6)" ::: "memory");
    } else {
      asm volatile("s_waitcnt vmcnt(0)" ::: "memory");
    }
    __builtin_amdgcn_s_barrier();
    __builtin_amdgcn_s_setprio(1);
    MFMA_Q(a1, b0, 1, 0);
    __builtin_amdgcn_s_setprio(0);
    __builtin_amdgcn_s_barrier();
  }

  // epilogue: C/D layout col=lane&15, row=quad*4+reg
#pragma unroll
  for (int mi = 0; mi < 8; ++mi)
#pragma unroll
    for (int ni = 0; ni < 4; ++ni)
#pragma unroll
      for (int r = 0; r < 4; ++r) {
        int row = tm0 + wm * 128 + mi * 16 + quad * 4 + r;
        int col = tn0 + wn * 64 + ni * 16 + l15;
        float v = acc[mi][ni][r];
        if (OUT_BF16) ((u16*)Cout)[(size_t)row * N + col] = f2b(v);
        else          ((float*)Cout)[(size_t)row * N + col] = v;
      }
}

// ---------------- RoPE in-place on q,k of qkv (bf16) ----------------
__global__ void rope_k(u16* __restrict__ qkv) {
  int idx = blockIdx.x * 256 + threadIdx.x;   // 0 .. 2^23-1
  int i = idx & 63;
  int h = (idx >> 6) & 15;
  int which = (idx >> 10) & 1;
  int t = (idx >> 11) & 2047;
  int b = idx >> 22;
  size_t base = (size_t)(b * T_ + t) * QKVW + which * 2048 + h * 128 + i;
  float t1 = b2f(qkv[base]), t2 = b2f(qkv[base + 64]);
  // div_i = 10000^(-i/64) ; log2(10000)/64 = 0.20762050593046439
  float ang = (float)t * exp2f(-(float)i * 0.20762050593046439f);
  float sn, cs;
  sincosf(ang, &sn, &cs);
  qkv[base]      = f2b(t1 * cs - t2 * sn);
  qkv[base + 64] = f2b(t2 * cs + t1 * sn);
}

// ---------------- transpose V -> Vt [B*H][D][T] (bf16) ----------------
__global__ __launch_bounds__(256) void vtrans(const u16* __restrict__ qkv, u16* __restrict__ vt) {
  __shared__ __align__(16) u16 ld[128][136];
  const int tt = blockIdx.x, bh = blockIdx.y;
  const int b = bh >> 4, h = bh & 15;
  const u16* vb = qkv + (size_t)b * T_ * QKVW + 4096 + h * 128;
  const int tid = threadIdx.x;
#pragma unroll
  for (int s = 0; s < 8; ++s) {
    int t = (tid >> 4) + s * 16;
    int d0 = (tid & 15) * 8;
    *(bf16x8*)&ld[t][d0] = *(const bf16x8*)(vb + (size_t)(tt * 128 + t) * QKVW + d0);
  }
  __syncthreads();
  u16* vout = vt + (size_t)bh * D_ * T_ + tt * 128;
#pragma unroll
  for (int s = 0; s < 8; ++s) {
    int d = (tid >> 4) + s * 16;
    int t0 = (tid & 15) * 8;
    u16x8 o;
#pragma unroll
    for (int j = 0; j < 8; ++j) o[j] = ld[t0 + j][d];
    *(u16x8*)(vout + (size_t)d * T_ + t0) = o;
  }
}

// ---------------- flash attention (causal, online softmax) ----------------
// R3: de-serialize softmax. R2 post-mortem: MfmaUtil 6.9% / VALUBusy 29% —
// the 32 shfl_xor (ds_swizzle) per tile_compute in 4-deep chains dominate.
// (a) lrow becomes a PER-LANE PARTIAL (each lane sums only its keys);
//     cross-lane reduced ONCE in the epilogue — removes 16 shfl/tile.
// (b) defer-max check via per-lane partial max + one __any ballot; the full
//     16-shfl max-reduce runs only on trigger tiles (first + rare growth).
//     NaN edge (-inf - -inf) votes false — masked lanes never trigger.
// (c) T5 setprio around both MFMA clusters.
// Causal pairing retained: block (bh,jp) owns jA=jp, jB=31-jp (33 units).
// NOTE reference gotcha: out = einsum('bhts,bshd->bhtd').reshape(B,T,C) is a
// FLAT reshape of (B,H,T,D): element (b,h,t,d) sits at ((b*H+h)*T+t)*D+d.
#define APW 72    // P tile row stride (u16)
__global__ __launch_bounds__(256, 2) void attn(const u16* __restrict__ qkv,
                                               const u16* __restrict__ vt,
                                               u16* __restrict__ obuf) {
  __shared__ __align__(16) u16 lK[2][64 * 128];    // 2 x 16 KB, swizzled
  __shared__ __align__(16) u16 lV[2][128 * 64];    // 2 x 16 KB, swizzled
  __shared__ __align__(16) u16 lP[64 * APW];       // 9 KB, wave-private rows
  const int tid = threadIdx.x, lane = tid & 63, w = tid >> 6;
  const int quad = lane >> 4, l15 = lane & 15;
  const int bh = blockIdx.x, jp = blockIdx.y;
  const int jA = jp, jB = 31 - jp;                 // jA in 0..15, jB in 16..31
  const int b = bh >> 4, h = bh & 15;
  const u16* qb = qkv + (size_t)b * T_ * QKVW + h * 128;
  const u16* kb = qb + 2048;
  const u16* vtb = vt + (size_t)bh * D_ * T_;

  bf16x8 qfA[4], qfB[4];
#pragma unroll
  for (int kk = 0; kk < 4; ++kk) {
    qfA[kk] = *(const bf16x8*)(qb + (size_t)(jA * 64 + w * 16 + l15) * QKVW + kk * 32 + quad * 8);
    qfB[kk] = *(const bf16x8*)(qb + (size_t)(jB * 64 + w * 16 + l15) * QKVW + kk * 32 + quad * 8);
  }

  f32x4 oA[8] = {}, oB[8] = {};
  float mA[4], lAr[4], mB[4], lBr[4];
#pragma unroll
  for (int r = 0; r < 4; ++r) {
    mA[r] = -__builtin_inff(); lAr[r] = 0.f;
    mB[r] = -__builtin_inff(); lBr[r] = 0.f;
  }
  const float sc = 0.08838834764831845f * 1.4426950408889634f;  // 1/sqrt(128) * log2(e)

  // stage K tile [64 key][128 d] and Vt tile [128 d][64 key] via global_load_lds,
  // linear LDS dest + inverse-swizzled global source (G4 3-bit XOR).
  auto stage = [&](int kt, int buf) {
#pragma unroll
    for (int s = 0; s < 4; ++s) {
      int ch = tid + s * 256;                        // 0..1023
      int kr = ch >> 4, kc = (ch & 15) ^ (kr & 7);   // K row 0..63, 16 chunks/row
      gl_lds16(kb + (size_t)(kt * 64 + kr) * QKVW + kc * 8, &lK[buf][ch * 8]);
      int vr = ch >> 3, vc = (ch & 7) ^ (vr & 7);    // V row 0..127, 8 chunks/row
      gl_lds16(vtb + (size_t)vr * T_ + kt * 64 + vc * 8, &lV[buf][ch * 8]);
    }
  };

  auto tile_compute = [&](const bf16x8* qf, f32x4* oacc, float* mrow, float* lrow,
                          int jw, int kt, int cb) {
    // S = Q K^T   (16 q-rows x 64 keys per wave)
    f32x4 sacc[4] = {};
#pragma unroll
    for (int kk = 0; kk < 4; ++kk) {
      bf16x8 kf[4];
#pragma unroll
      for (int nj = 0; nj < 4; ++nj) {
        int r = nj * 16 + l15;
        kf[nj] = *(const bf16x8*)&lK[cb][r * 128 + ((kk * 32 + quad * 8) ^ ((r & 7) << 3))];
      }
      __builtin_amdgcn_s_setprio(1);
#pragma unroll
      for (int nj = 0; nj < 4; ++nj)
        sacc[nj] = __builtin_amdgcn_mfma_f32_16x16x32_bf16(qf[kk], kf[nj], sacc[nj], 0, 0, 0);
      __builtin_amdgcn_s_setprio(0);
    }
    const bool diag = (kt == jw);
#pragma unroll
    for (int nj = 0; nj < 4; ++nj) {
      int key = nj * 16 + l15;                 // local key 0..63
#pragma unroll
      for (int r = 0; r < 4; ++r) {
        float s = sacc[nj][r] * sc;
        if (diag) {
          int qrow = w * 16 + quad * 4 + r;    // local q 0..63
          if (key > qrow) s = -__builtin_inff();
        }
        sacc[nj][r] = s;
      }
    }
    // per-lane partial max + single ballot defer-check (T13)
    float pm[4];
#pragma unroll
    for (int r = 0; r < 4; ++r)
      pm[r] = fmaxf(fmaxf(sacc[0][r], sacc[1][r]), fmaxf(sacc[2][r], sacc[3][r]));
    float dmax = fmaxf(fmaxf(pm[0] - mrow[0], pm[1] - mrow[1]),
                       fmaxf(pm[2] - mrow[2], pm[3] - mrow[3]));
    if (__any(dmax > 11.5f)) {                 // rare: real max growth
#pragma unroll
      for (int r = 0; r < 4; ++r) {
        float rm = pm[r];
        rm = fmaxf(rm, __shfl_xor(rm, 1));
        rm = fmaxf(rm, __shfl_xor(rm, 2));
        rm = fmaxf(rm, __shfl_xor(rm, 4));
        rm = fmaxf(rm, __shfl_xor(rm, 8));
        float mold = mrow[r];
        float mnew = fmaxf(mold, rm);
        float alpha = exp2f(mold - mnew);
#pragma unroll
        for (int nd = 0; nd < 8; ++nd) oacc[nd][r] *= alpha;
        lrow[r] *= alpha;
        mrow[r] = mnew;
      }
    }
#pragma unroll
    for (int r = 0; r < 4; ++r) {
      int prow = w * 16 + quad * 4 + r;        // wave-private P row
      float rs = 0.f;
#pragma unroll
      for (int nj = 0; nj < 4; ++nj) {
        float p = exp2f(sacc[nj][r] - mrow[r]);
        rs += p;
        lP[prow * APW + nj * 16 + l15] = f2b(p);
      }
      lrow[r] += rs;                           // PER-LANE partial (no shfl!)
    }
    // PV: O += P * V  (P rows wave-private — no barrier needed)
#pragma unroll
    for (int kk = 0; kk < 2; ++kk) {
      bf16x8 pf, vf[8];
      pf = *(const bf16x8*)&lP[(w * 16 + l15) * APW + kk * 32 + quad * 8];
#pragma unroll
      for (int nd = 0; nd < 8; ++nd) {
        int r = nd * 16 + l15;
        vf[nd] = *(const bf16x8*)&lV[cb][r * 64 + ((kk * 32 + quad * 8) ^ ((r & 7) << 3))];
      }
      __builtin_amdgcn_s_setprio(1);
#pragma unroll
      for (int nd = 0; nd < 8; ++nd)
        oacc[nd] = __builtin_amdgcn_mfma_f32_16x16x32_bf16(pf, vf[nd], oacc[nd], 0, 0, 0);
      __builtin_amdgcn_s_setprio(0);
    }
  };

  stage(0, 0);
  __syncthreads();   // drains vmcnt (implicit in __syncthreads)

  for (int kt = 0; kt <= jB; ++kt) {
    int cb = kt & 1;
    if (kt < jB) stage(kt + 1, cb ^ 1);       // overlap next-tile DMA with compute
    tile_compute(qfB, oB, mB, lBr, jB, kt, cb);
    if (kt <= jA) tile_compute(qfA, oA, mA, lAr, jA, kt, cb);
    __syncthreads();                          // drains stage DMA + LDS, swap bufs
  }

  // single cross-lane reduction of the per-lane l partials
#pragma unroll
  for (int r = 0; r < 4; ++r) {
    float sA = lAr[r], sB = lBr[r];
    sA += __shfl_xor(sA, 1); sB += __shfl_xor(sB, 1);
    sA += __shfl_xor(sA, 2); sB += __shfl_xor(sB, 2);
    sA += __shfl_xor(sA, 4); sB += __shfl_xor(sB, 4);
    sA += __shfl_xor(sA, 8); sB += __shfl_xor(sB, 8);
    lAr[r] = sA; lBr[r] = sB;
  }

  // epilogue: O / l -> bf16, REFERENCE-MATCHED layout [B*H][T][D] (see note)
#pragma unroll
  for (int nd = 0; nd < 8; ++nd)
#pragma unroll
    for (int r = 0; r < 4; ++r) {
      int dcol = nd * 16 + l15;
      int qrB = jB * 64 + w * 16 + quad * 4 + r;
      obuf[((size_t)bh * T_ + qrB) * D_ + dcol] = f2b(oB[nd][r] / lBr[r]);
      int qrA = jA * 64 + w * 16 + quad * 4 + r;
      obuf[((size_t)bh * T_ + qrA) * D_ + dcol] = f2b(oA[nd][r] / lAr[r]);
    }
}

extern "C" void kernel_launch(void* const* d_in, const int* in_sizes, int n_in,
                              void* d_out, int out_size, void* d_ws, size_t ws_size,
                              hipStream_t stream) {
  const float* x = (const float*)d_in[0];
  const float* Wqkv = (const float*)d_in[1];
  const float* Wout = (const float*)d_in[2];
  float* out = (float*)d_out;
  char* ws = (char*)d_ws;

  // workspace layout (bytes):
  //   [0,            16777216)  xb (x bf16)   -- later reused as Ob (attn out bf16)
  //   [16777216,     41943040)  Wqkv_t bf16   -- later reused as Wout_t bf16
  //   [41943040,     92274688)  qkv bf16 [4096][6144]
  //   [92274688,    109051904)  Vt bf16 [B*H][128][2048]
  u16* xb   = (u16*)ws;
  u16* wqt  = (u16*)(ws + 16777216);
  u16* qkvb = (u16*)(ws + 41943040);
  u16* vtb  = (u16*)(ws + 92274688);
  u16* wot  = wqt;   // alias: cast after GEMM1 consumed Wqkv_t
  u16* ob   = xb;    // alias: attn output after GEMM1 consumed xb

  castbf<<<4096, 256, 0, stream>>>(x, xb);                                  // 8.4M elems
  castT<<<dim3(96, 32), 256, 0, stream>>>(Wqkv, wqt, 2048, 6144);
  gemm256<1><<<dim3(384), 512, 0, stream>>>(xb, wqt, qkvb, 4096, 6144, 2048);
  castT<<<dim3(32, 32), 256, 0, stream>>>(Wout, wot, 2048, 2048);
  rope_k<<<32768, 256, 0, stream>>>(qkvb);
  vtrans<<<dim3(16, 32), 256, 0, stream>>>(qkvb, vtb);
  attn<<<dim3(32, 16), 256, 0, stream>>>(qkvb, vtb, ob);   // (bh, jpair)
  gemm256<0><<<dim3(128), 512, 0, stream>>>(ob, wot, out, 4096, 2048, 2048);
}